// Round 8
// baseline (41.782 us; speedup 1.0000x reference)
//
#include <hip/hip_runtime.h>
#include <hip/hip_bf16.h>
#include <math.h>

#define D 256
#define NPROTO 1024
#define WR 13
#define WC 18
#define WJ (WR * WC)
#define JSUB 59                    // ceil(WJ/4)
#define GMAT_BLOCKS (NPROTO / 4)   // 256
#define XPREP_BLOCKS (16384 / 8)   // 2048

#define WAITVM(N) asm volatile("s_waitcnt vmcnt(" #N ")" ::: "memory")

typedef __attribute__((ext_vector_type(8))) short short8;
typedef __attribute__((ext_vector_type(4))) short s16x4;
typedef __attribute__((ext_vector_type(4))) float f32x4;

__device__ __forceinline__ short f2bf(float f) {
    union { __hip_bfloat16 b; short s; } u;
    u.b = __float2bfloat16(f);
    return u.s;
}

__device__ __forceinline__ void gload_lds16(void* lds, const void* g) {
    __builtin_amdgcn_global_load_lds(
        (const __attribute__((address_space(1))) unsigned*)g,
        (__attribute__((address_space(3))) unsigned*)lds, 16, 0, 0);
}

// ---- hex-grid neighborhood H[i,j] on the fly (fp64, matches np ref) ----
__device__ __forceinline__ void proto_pos(int idx, double& x, double& y) {
    int r = idx >> 5, c = idx & 31;
    x = (double)c + 0.5 * (double)(r & 1);
    y = (double)r * 0.86602540378443864676;  // sqrt(3)/2
}

__device__ __forceinline__ float hval(int i, int j) {
    double xi, yi, xj, yj;
    proto_pos(i, xi, yi);
    proto_pos(j, xj, yj);
    double dx0 = xi - xj, dy0 = yi - yj;
    const double W = 32.0;
    const double Hh = 27.712812921102035;  // 32*sqrt(3)/2
    double best = 1e300;
#pragma unroll
    for (int sx = -1; sx <= 1; ++sx) {
        double dx = dx0 + (double)sx * W;
#pragma unroll
        for (int sy = -1; sy <= 1; ++sy) {
            double dy = dy0 + (double)sy * Hh;
            double d2 = dx * dx + dy * dy;
            best = fmin(best, d2);
        }
    }
    return (float)exp(-0.5 * best);
}

// ---- prep: role-split single kernel (R5 verbatim).
//  blocks [0, 256):      gmat — Gb = bf16(H@P) pre-swizzled, hsum, hp2
//  blocks [256, 2304):   xprep — Xg = bf16(X) pre-swizzled, x2, out=+inf ----
__global__ void __launch_bounds__(256) prep_kernel(
    const float* __restrict__ X, const float* __restrict__ P,
    short* __restrict__ Xg, short* __restrict__ Gb,
    float* __restrict__ x2, float* __restrict__ hsum, float* __restrict__ hp2,
    unsigned* __restrict__ out) {
    int t = threadIdx.x;
    int bx = blockIdx.x;

    if (bx >= GMAT_BLOCKS) {
        // ---------------- xprep ----------------
        int row = (bx - GMAT_BLOCKS) * 8 + (t >> 5);
        int g = t & 31;
        const float4* src = reinterpret_cast<const float4*>(X + (size_t)row * D) + g * 2;
        float4 a = src[0], b = src[1];
        float s = a.x * a.x + a.y * a.y + a.z * a.z + a.w * a.w +
                  b.x * b.x + b.y * b.y + b.z * b.z + b.w * b.w;
        s += __shfl_xor(s, 1);
        s += __shfl_xor(s, 2);
        s += __shfl_xor(s, 4);
        s += __shfl_xor(s, 8);
        s += __shfl_xor(s, 16);
        if (g == 0) x2[row] = s;
        short8 w;
        w[0] = f2bf(a.x); w[1] = f2bf(a.y); w[2] = f2bf(a.z); w[3] = f2bf(a.w);
        w[4] = f2bf(b.x); w[5] = f2bf(b.y); w[6] = f2bf(b.z); w[7] = f2bf(b.w);
        int sw = ((g * 8) & 63) ^ ((row & 7) << 3);  // short-index swizzle in 64-chunk
        *reinterpret_cast<short8*>(Xg + (size_t)row * D + ((g >> 3) << 6) + sw) = w;
        if (t < 8) out[(bx - GMAT_BLOCKS) * 8 + t] = 0x7f800000u;  // +inf
        return;
    }

    // ---------------- gmat ----------------
    __shared__ float ht[4][WJ];
    __shared__ int jrow[WJ];
    __shared__ __align__(16) float gpart[4][4][256];  // wave x proto x d, 16KB
    __shared__ float hqred[4][4];                     // wave x proto
    __shared__ float hsred[4][4];
    int i0 = bx * 4;
    int r0 = i0 >> 5, c0 = i0 & 31;

    for (int u = t; u < WJ; u += 256) {
        int jr = (r0 + (u / WC) - 6 + 32) & 31;
        int jc = (c0 + (u % WC) - 7 + 32) & 31;
        int j = jr * 32 + jc;
        jrow[u] = j;
#pragma unroll
        for (int s = 0; s < 4; ++s) ht[s][u] = hval(i0 + s, j);
    }
    __syncthreads();

    int w = t >> 6, lane = t & 63;
    int j0 = w * JSUB;
    int j1 = (j0 + JSUB < WJ) ? j0 + JSUB : WJ;
    f32x4 g[4] = {{0.f, 0.f, 0.f, 0.f}, {0.f, 0.f, 0.f, 0.f},
                  {0.f, 0.f, 0.f, 0.f}, {0.f, 0.f, 0.f, 0.f}};
    float hqp[4] = {0.f, 0.f, 0.f, 0.f};
    float hsp[4] = {0.f, 0.f, 0.f, 0.f};
    for (int u = j0; u < j1; ++u) {
        f32x4 pv = *reinterpret_cast<const f32x4*>(P + (size_t)jrow[u] * D + lane * 4);
        float q = pv[0] * pv[0] + pv[1] * pv[1] + pv[2] * pv[2] + pv[3] * pv[3];
#pragma unroll
        for (int s = 0; s < 4; ++s) {
            float h = ht[s][u];
            g[s][0] = fmaf(h, pv[0], g[s][0]);
            g[s][1] = fmaf(h, pv[1], g[s][1]);
            g[s][2] = fmaf(h, pv[2], g[s][2]);
            g[s][3] = fmaf(h, pv[3], g[s][3]);
            hqp[s] = fmaf(h, q, hqp[s]);
            hsp[s] += h;  // lane-uniform
        }
    }
#pragma unroll
    for (int s = 0; s < 4; ++s)
        *reinterpret_cast<f32x4*>(&gpart[w][s][lane * 4]) = g[s];
#pragma unroll
    for (int s = 0; s < 4; ++s) {
#pragma unroll
        for (int off = 1; off < 64; off <<= 1) hqp[s] += __shfl_xor(hqp[s], off);
    }
    if (lane == 0) {
#pragma unroll
        for (int s = 0; s < 4; ++s) { hqred[w][s] = hqp[s]; hsred[w][s] = hsp[s]; }
    }
    __syncthreads();

    {
        int s = t >> 6;
        f32x4 gs = *reinterpret_cast<const f32x4*>(&gpart[0][s][lane * 4]);
#pragma unroll
        for (int ww = 1; ww < 4; ++ww) {
            f32x4 gp = *reinterpret_cast<const f32x4*>(&gpart[ww][s][lane * 4]);
            gs[0] += gp[0]; gs[1] += gp[1]; gs[2] += gp[2]; gs[3] += gp[3];
        }
        int i = i0 + s;
        s16x4 wv = {f2bf(gs[0]), f2bf(gs[1]), f2bf(gs[2]), f2bf(gs[3])};
        int sw = ((lane * 4) & 63) ^ ((i & 7) << 3);
        *reinterpret_cast<s16x4*>(Gb + (size_t)i * D + ((lane >> 4) << 6) + sw) = wv;
    }
    if (t < 4) {
        hsum[i0 + t] = hsred[0][t] + hsred[1][t] + hsred[2][t] + hsred[3][t];
    } else if (t < 8) {
        int s = t - 4;
        hp2[i0 + s] = hqred[0][s] + hqred[1][s] + hqred[2][s] + hqred[3][s];
    }
}

// ---- som6: R5's som5 + XCD-chunked bijective block swizzle (T1).
//      block tile 128n x 256i, 512 blocks (2/CU), counted-vmcnt 8 phases. ----
__global__ void __launch_bounds__(256, 2) som6_kernel(
    const short* __restrict__ Xg, const short* __restrict__ Gb,
    const float* __restrict__ x2, const float* __restrict__ hsum,
    const float* __restrict__ hp2, unsigned* __restrict__ out) {
    __shared__ __align__(16) short Xs[2][128 * 64];  // 16KB each
    __shared__ __align__(16) short Gs[2][128 * 64];
    __shared__ float red[2][128];

    const int t = threadIdx.x;
    const int lane = t & 63;
    const int wid = t >> 6;
    const int wr = wid >> 1;  // n half (64 rows)
    const int wc = wid & 1;   // i half (64 cols within subtile)
    const int lm = lane & 15;
    const int lq = lane >> 4;

    // XCD-chunked bijective swizzle: 512 blocks = 8 XCDs x 64.
    // XCD k (lin % 8 == k) covers nb in [16k, 16k+16), all 4 ib chunks ->
    // per-XCD working set = 1MB Xg slice + 512KB Gb (L2-resident).
    const int lin = blockIdx.y * 128 + blockIdx.x;  // wait: grid is (128,4); linear = x + y*128
    const int w512 = ((lin & 7) << 6) + (lin >> 3);
    const int nb = w512 >> 2;   // 0..127
    const int ibb = w512 & 3;   // 0..3
    const int n0 = nb * 128;
    const int ib0 = ibb * 256;

    f32x4 acc[2][4][4];
#pragma unroll
    for (int it = 0; it < 2; ++it)
#pragma unroll
        for (int m = 0; m < 4; ++m)
#pragma unroll
            for (int n = 0; n < 4; ++n) acc[it][m][n] = (f32x4){0.f, 0.f, 0.f, 0.f};

    auto stage_X = [&](int xb, int kt) {
#pragma unroll
        for (int q = 0; q < 4; ++q) {
            int row = q * 32 + (t >> 3);
            gload_lds16((char*)(&Xs[xb][0]) + q * 4096 + t * 16,
                        Xg + (size_t)(n0 + row) * D + kt * 64 + (t & 7) * 8);
        }
    };
    auto stage_G = [&](int gb, int kt, int it) {
#pragma unroll
        for (int q = 0; q < 4; ++q) {
            int row = q * 32 + (t >> 3);
            gload_lds16((char*)(&Gs[gb][0]) + q * 4096 + t * 16,
                        Gb + (size_t)(ib0 + it * 128 + row) * D + kt * 64 + (t & 7) * 8);
        }
    };

    auto compute = [&](int xb, int gb, int it) {
#pragma unroll
        for (int kk = 0; kk < 2; ++kk) {
            const int off = (kk * 32 + lq * 8) ^ ((lm & 7) << 3);  // short idx
            short8 a[4], b[4];
#pragma unroll
            for (int m = 0; m < 4; ++m)
                a[m] = *reinterpret_cast<const short8*>(
                    &Xs[xb][(wr * 64 + m * 16 + lm) * 64 + off]);
#pragma unroll
            for (int n = 0; n < 4; ++n)
                b[n] = *reinterpret_cast<const short8*>(
                    &Gs[gb][(wc * 64 + n * 16 + lm) * 64 + off]);
            __builtin_amdgcn_s_setprio(1);
#pragma unroll
            for (int m = 0; m < 4; ++m)
#pragma unroll
                for (int n = 0; n < 4; ++n)
                    acc[it][m][n] = __builtin_amdgcn_mfma_f32_16x16x32_bf16(a[m], b[n], acc[it][m][n], 0, 0, 0);
            __builtin_amdgcn_s_setprio(0);
        }
    };

    // prologue: stage phase 0 (8 VMEM instrs outstanding)
    stage_G(0, 0, 0);
    stage_X(0, 0);

#pragma unroll
    for (int p = 0; p < 8; ++p) {
        if (p < 7) {
            const int pn = p + 1, ktn = pn >> 1, itn = pn & 1;
            if (itn == 0) stage_X(ktn & 1, ktn);   // one phase ahead of use
            stage_G(pn & 1, ktn, itn);
        }
        if (p == 7) { WAITVM(0); }
        else if (p & 1) { WAITVM(8); }
        else { WAITVM(4); }
        __builtin_amdgcn_sched_barrier(0);
        __builtin_amdgcn_s_barrier();
        compute((p >> 1) & 1, p & 1, p & 1);
        __builtin_amdgcn_s_barrier();
    }

    // ---- epilogue: e = hsum*x2 + hp2 - 2*acc; min over all 256 i ----
    float x2v[4][4];
#pragma unroll
    for (int m = 0; m < 4; ++m)
#pragma unroll
        for (int j = 0; j < 4; ++j)
            x2v[m][j] = x2[n0 + wr * 64 + m * 16 + lq * 4 + j];

    float rmin[4][4];
#pragma unroll
    for (int m = 0; m < 4; ++m)
#pragma unroll
        for (int j = 0; j < 4; ++j) rmin[m][j] = 3.4e38f;

#pragma unroll
    for (int it = 0; it < 2; ++it)
#pragma unroll
        for (int ni = 0; ni < 4; ++ni) {
            int ig = ib0 + it * 128 + wc * 64 + ni * 16 + lm;
            float hs = hsum[ig];
            float hq = hp2[ig];
#pragma unroll
            for (int m = 0; m < 4; ++m)
#pragma unroll
                for (int j = 0; j < 4; ++j) {
                    float e = fmaf(hs, x2v[m][j], hq) - 2.0f * acc[it][m][ni][j];
                    rmin[m][j] = fminf(rmin[m][j], e);
                }
        }

#pragma unroll
    for (int m = 0; m < 4; ++m)
#pragma unroll
        for (int j = 0; j < 4; ++j) {
            float v = rmin[m][j];
            v = fminf(v, __shfl_xor(v, 1));
            v = fminf(v, __shfl_xor(v, 2));
            v = fminf(v, __shfl_xor(v, 4));
            v = fminf(v, __shfl_xor(v, 8));
            rmin[m][j] = v;
        }
    if (lm == 0) {
#pragma unroll
        for (int m = 0; m < 4; ++m)
#pragma unroll
            for (int j = 0; j < 4; ++j)
                red[wc][wr * 64 + m * 16 + lq * 4 + j] = rmin[m][j];
    }
    __syncthreads();
    if (t < 128) {
        float v = fminf(red[0][t], red[1][t]);
        atomicMin(out + n0 + t, __float_as_uint(0.5f * v));
    }
}

extern "C" void kernel_launch(void* const* d_in, const int* in_sizes, int n_in,
                              void* d_out, int out_size, void* d_ws, size_t ws_size,
                              hipStream_t stream) {
    const float* X = (const float*)d_in[0];  // [16384, 256]
    const float* P = (const float*)d_in[1];  // [1024, 256]
    unsigned* out = (unsigned*)d_out;        // [1, 16384] f32 as uint
    int N = in_sizes[0] / D;                 // 16384

    float* ws = (float*)d_ws;
    float* hsum = ws + 1024;             // 1024 f32
    float* hp2 = ws + 2048;              // 1024 f32
    float* x2 = ws + 4096;               // 16384 f32
    short* Gb = (short*)(ws + 32768);    // 1024*256 bf16 pre-swizzled (512KB)
    short* Xg = (short*)(ws + 262144);   // 16384*256 bf16 pre-swizzled (8.4MB)

    prep_kernel<<<GMAT_BLOCKS + XPREP_BLOCKS, 256, 0, stream>>>(
        X, P, Xg, Gb, x2, hsum, hp2, out);
    // MEASUREMENT ROUND: som6 launched TWICE (idempotent atomicMin; out
    // re-init'd by prep each call). som6 duration ~= T8 - T5 directly.
    som6_kernel<<<dim3(128, 4), 256, 0, stream>>>(Xg, Gb, x2, hsum, hp2, out);
    som6_kernel<<<dim3(128, 4), 256, 0, stream>>>(Xg, Gb, x2, hsum, hp2, out);
}